// Round 11
// baseline (160.959 us; speedup 1.0000x reference)
//
#include <hip/hip_runtime.h>

// ===== DIAGNOSTIC ROUND: internal kernel repeats (idempotent) to surface
// per-kernel durations + counters above the 40us harness poison fills. =====

#define IN_F  1024
#define HID_F 1024
#define OUT_F 512
#define BATCH 128
#define REP_PRE 12
#define REP_K1  8
#define REP_K2  10

__device__ __forceinline__ float sigm(float v) { return 1.0f / (1.0f + __expf(-v)); }

typedef __attribute__((ext_vector_type(8))) float f32x8;
typedef __attribute__((ext_vector_type(4))) float f32x4;

__device__ __forceinline__ f32x8 sld8(const float* p, int off_bytes) {
    f32x8 r;
    asm volatile("s_load_dwordx8 %0, %1, %2" : "=&s"(r) : "s"(p), "s"(off_bytes));
    return r;
}
__device__ __forceinline__ f32x4 sld4(const float* p, int off_bytes) {
    f32x4 r;
    asm volatile("s_load_dwordx4 %0, %1, %2" : "=&s"(r) : "s"(p), "s"(off_bytes));
    return r;
}
__device__ __forceinline__ void swait8x4(f32x8& a, f32x8& b, f32x8& c, f32x8& d) {
    asm volatile("s_waitcnt lgkmcnt(0)" : "+s"(a), "+s"(b), "+s"(c), "+s"(d));
}
__device__ __forceinline__ void swait4x4(f32x4& a, f32x4& b, f32x4& c, f32x4& d) {
    asm volatile("s_waitcnt lgkmcnt(0)" : "+s"(a), "+s"(b), "+s"(c), "+s"(d));
}
__device__ __forceinline__ void swait1(f32x8& a) {
    asm volatile("s_waitcnt lgkmcnt(0)" : "+s"(a));
}

__global__ __launch_bounds__(256) void kPre(const float* __restrict__ x,
                                            const float* __restrict__ w1,
                                            const float* __restrict__ s1,
                                            const float* __restrict__ w2,
                                            float* __restrict__ xt,
                                            float* __restrict__ Dm,
                                            float* __restrict__ PA16,
                                            float* __restrict__ w2s) {
    const int bx = blockIdx.x, tid = threadIdx.x;
    if (bx < 256) {
        const int sc = bx >> 2;
        const int j  = (bx & 3) * 256 + tid;
        const float* w1l = w1; const float* s1l = s1;
        for (int rep = 0; rep < REP_PRE; ++rep) {
            asm volatile("" : "+s"(w1l), "+s"(s1l));   // defeat CSE across reps
            float pa = 1.0f;
#pragma unroll 4
            for (int ii = 0; ii < 16; ++ii) {
                const int i = sc * 16 + ii;
                const float w = sigm(w1l[(size_t)i * HID_F + j]);
                const float s = sigm(s1l[(size_t)i * HID_F + j]);
                const float A = 1.0f - w * s;
                const float C = w * (2.0f * s - 1.0f);
                Dm[(size_t)i * HID_F + j] = C / A;
                pa *= A;
            }
            PA16[(size_t)sc * HID_F + j] = pa;
        }
    } else if (bx < 768) {
        const float* w2l = w2;
        for (int rep = 0; rep < REP_PRE; ++rep) {
            asm volatile("" : "+s"(w2l));
            const int e = ((bx - 256) * 256 + tid) * 4;
            const float4 v = *(const float4*)(w2l + e);
            float4 r;
            r.x = sigm(v.x); r.y = sigm(v.y); r.z = sigm(v.z); r.w = sigm(v.w);
            *(float4*)(w2s + e) = r;
        }
    } else {
        __shared__ float tile[32][33];
        const float* xl = x;
        for (int rep = 0; rep < REP_PRE; ++rep) {
            asm volatile("" : "+s"(xl));
            const int bt = bx - 768;
            const int i0 = (bt & 31) * 32, b0 = (bt >> 5) * 32;
            const int tx = tid & 31, ty = tid >> 5;
            __syncthreads();   // WAR guard across reps
#pragma unroll
            for (int r = 0; r < 32; r += 8)
                tile[ty + r][tx] = xl[(size_t)(b0 + ty + r) * IN_F + i0 + tx];
            __syncthreads();
#pragma unroll
            for (int r = 0; r < 32; r += 8)
                xt[(size_t)(i0 + ty + r) * BATCH + b0 + tx] = tile[tx][ty + r];
        }
    }
}

__global__ __launch_bounds__(1024, 4) void k1h(const float* __restrict__ Dm,
                                               const float* __restrict__ PA16,
                                               const float* __restrict__ xt,
                                               float* __restrict__ ht) {
    __shared__ float ps[16][8][64];
    const int tid  = threadIdx.x;
    const int lane = tid & 63;
    const int wvu  = __builtin_amdgcn_readfirstlane(tid >> 6);
    const int j0   = blockIdx.x * 8;
    const int bh   = blockIdx.y;
    const int b    = bh * 64 + lane;
    const int i0   = wvu * 64;

    const float* Dml = Dm; const float* PAl = PA16; const float* xtl = xt;
    for (int rep = 0; rep < REP_K1; ++rep) {
        asm volatile("" : "+s"(Dml), "+s"(PAl), "+s"(xtl));
        float acc[8];
#pragma unroll
        for (int k = 0; k < 8; ++k) acc[k] = 1.0f;
        const float* xp = xtl + (size_t)i0 * BATCH + b;
        const int dbase = (i0 * HID_F + j0) * 4;
#pragma unroll 1
        for (int sc = 0; sc < 4; ++sc) {
            f32x8 pa = sld8(PAl, ((wvu * 4 + sc) * HID_F + j0) * 4);
#pragma unroll 1
            for (int bt = 0; bt < 4; ++bt) {
                const int ib = sc * 16 + bt * 4;
                f32x8 d0 = sld8(Dml, dbase + (ib + 0) * (HID_F * 4));
                f32x8 d1 = sld8(Dml, dbase + (ib + 1) * (HID_F * 4));
                f32x8 d2 = sld8(Dml, dbase + (ib + 2) * (HID_F * 4));
                f32x8 d3 = sld8(Dml, dbase + (ib + 3) * (HID_F * 4));
                const float x0 = xp[(ib + 0) * BATCH];
                const float x1 = xp[(ib + 1) * BATCH];
                const float x2 = xp[(ib + 2) * BATCH];
                const float x3 = xp[(ib + 3) * BATCH];
                swait8x4(d0, d1, d2, d3);
#pragma unroll
                for (int jj = 0; jj < 8; ++jj) {
                    acc[jj] *= fmaf(x0, d0[jj], 1.0f);
                    acc[jj] *= fmaf(x1, d1[jj], 1.0f);
                    acc[jj] *= fmaf(x2, d2[jj], 1.0f);
                    acc[jj] *= fmaf(x3, d3[jj], 1.0f);
                }
            }
            swait1(pa);
#pragma unroll
            for (int jj = 0; jj < 8; ++jj) acc[jj] *= pa[jj];
        }
        __syncthreads();   // WAR guard before rewriting ps
#pragma unroll
        for (int jj = 0; jj < 8; ++jj) ps[wvu][jj][lane] = acc[jj];
        __syncthreads();
        if (tid < 512) {
            const int j = tid >> 6, bb = tid & 63;
            float p = 1.0f;
#pragma unroll
            for (int w = 0; w < 16; ++w) p *= ps[w][j][bb];
            ht[(size_t)(j0 + j) * BATCH + bh * 64 + bb] = p;
        }
    }
}

__global__ __launch_bounds__(1024, 4) void k2o(const float* __restrict__ w2s,
                                               const float* __restrict__ ht,
                                               float* __restrict__ out) {
    __shared__ float ps2[16][4][64];
    const int tid  = threadIdx.x;
    const int lane = tid & 63;
    const int wvu  = __builtin_amdgcn_readfirstlane(tid >> 6);
    const int o0   = blockIdx.x * 4;
    const int bh   = blockIdx.y;
    const int b    = bh * 64 + lane;
    const int j0w  = wvu * 64;

    const float* wl = w2s; const float* hl = ht;
    for (int rep = 0; rep < REP_K2; ++rep) {
        asm volatile("" : "+s"(wl), "+s"(hl));
        float acc[4] = {1.0f, 1.0f, 1.0f, 1.0f};
        const float* hp = hl + (size_t)j0w * BATCH + b;
        const int wbase = (j0w * OUT_F + o0) * 4;
#pragma unroll 1
        for (int bt = 0; bt < 16; ++bt) {
            const int jb = bt * 4;
            f32x4 w0 = sld4(wl, wbase + (jb + 0) * (OUT_F * 4));
            f32x4 w1 = sld4(wl, wbase + (jb + 1) * (OUT_F * 4));
            f32x4 w2_ = sld4(wl, wbase + (jb + 2) * (OUT_F * 4));
            f32x4 w3 = sld4(wl, wbase + (jb + 3) * (OUT_F * 4));
            const float h0 = hp[(jb + 0) * BATCH];
            const float h1 = hp[(jb + 1) * BATCH];
            const float h2 = hp[(jb + 2) * BATCH];
            const float h3 = hp[(jb + 3) * BATCH];
            swait4x4(w0, w1, w2_, w3);
#pragma unroll
            for (int oo = 0; oo < 4; ++oo) {
                acc[oo] *= fmaf(-h0, w0[oo], 1.0f);
                acc[oo] *= fmaf(-h1, w1[oo], 1.0f);
                acc[oo] *= fmaf(-h2, w2_[oo], 1.0f);
                acc[oo] *= fmaf(-h3, w3[oo], 1.0f);
            }
        }
        __syncthreads();   // WAR guard
#pragma unroll
        for (int oo = 0; oo < 4; ++oo) ps2[wvu][oo][lane] = acc[oo];
        __syncthreads();
        if (tid < 256) {
            const int o = tid >> 6, bb = tid & 63;
            float p = 1.0f;
#pragma unroll
            for (int w = 0; w < 16; ++w) p *= ps2[w][o][bb];
            out[(size_t)(bh * 64 + bb) * OUT_F + o0 + o] = 1.0f - p;
        }
    }
}

extern "C" void kernel_launch(void* const* d_in, const int* in_sizes, int n_in,
                              void* d_out, int out_size, void* d_ws, size_t ws_size,
                              hipStream_t stream) {
    const float* x  = (const float*)d_in[0];
    const float* w1 = (const float*)d_in[1];
    const float* s1 = (const float*)d_in[2];
    const float* w2 = (const float*)d_in[3];
    float* out = (float*)d_out;

    float* Dm   = (float*)d_ws;
    float* PA16 = Dm + (size_t)IN_F * HID_F;
    float* w2s  = PA16 + (size_t)64 * HID_F;
    float* xt   = w2s + (size_t)HID_F * OUT_F;
    float* ht   = xt + (size_t)IN_F * BATCH;

    kPre<<<896, 256, 0, stream>>>(x, w1, s1, w2, xt, Dm, PA16, w2s);
    k1h<<<dim3(HID_F / 8, 2), 1024, 0, stream>>>(Dm, PA16, xt, ht);
    k2o<<<dim3(OUT_F / 4, 2), 1024, 0, stream>>>(w2s, ht, out);
}

// Round 12
// 34.282 us; speedup vs baseline: 4.6952x; 4.6952x over previous
//
#include <hip/hip_runtime.h>

#define IN_F  1024
#define HID_F 1024
#define OUT_F 512
#define BATCH 128

__device__ __forceinline__ float sigm(float v) { return 1.0f / (1.0f + __expf(-v)); }

typedef __attribute__((ext_vector_type(8))) float f32x8;
typedef __attribute__((ext_vector_type(4))) float f32x4;
typedef __attribute__((ext_vector_type(2))) float f32x2;

// Scalar-pipe broadcast loads (wave-uniform address -> SGPRs). SMEM is
// out-of-order; lgkmcnt(0) batched waits; tied "+s" orders consumers.
__device__ __forceinline__ f32x8 sld8(const float* p, int off_bytes) {
    f32x8 r;
    asm volatile("s_load_dwordx8 %0, %1, %2" : "=&s"(r) : "s"(p), "s"(off_bytes));
    return r;
}
__device__ __forceinline__ f32x4 sld4(const float* p, int off_bytes) {
    f32x4 r;
    asm volatile("s_load_dwordx4 %0, %1, %2" : "=&s"(r) : "s"(p), "s"(off_bytes));
    return r;
}
__device__ __forceinline__ void swait8x8(f32x8& a, f32x8& b, f32x8& c, f32x8& d,
                                         f32x8& e, f32x8& f, f32x8& g, f32x8& h) {
    asm volatile("s_waitcnt lgkmcnt(0)"
                 : "+s"(a), "+s"(b), "+s"(c), "+s"(d),
                   "+s"(e), "+s"(f), "+s"(g), "+s"(h));
}
__device__ __forceinline__ void swait4x8(f32x4& a, f32x4& b, f32x4& c, f32x4& d,
                                         f32x4& e, f32x4& f, f32x4& g, f32x4& h) {
    asm volatile("s_waitcnt lgkmcnt(0)"
                 : "+s"(a), "+s"(b), "+s"(c), "+s"(d),
                   "+s"(e), "+s"(f), "+s"(g), "+s"(h));
}

__device__ __forceinline__ f32x2 pair8(const f32x8& v, int k) {
    return f32x2{v[2 * k], v[2 * k + 1]};
}
__device__ __forceinline__ f32x2 pair4(const f32x4& v, int k) {
    return f32x2{v[2 * k], v[2 * k + 1]};
}

// kPre: [0,64):   per (i,j): A=1-ws, C=w(2s-1); D2 pair-interleaved [i/2][j]
//                 = {C/A(i even), C/A(i odd)}; PA64[i/64][j] = prod A over 64-i.
//       [64,192): W22 pair-interleaved [j/2][o] = {sigm(w2[2jp]), sigm(w2[2jp+1])}
//       [192,320): transpose x -> xt[1024][128]
__global__ __launch_bounds__(256) void kPre(const float* __restrict__ x,
                                            const float* __restrict__ w1,
                                            const float* __restrict__ s1,
                                            const float* __restrict__ w2,
                                            float* __restrict__ xt,
                                            float* __restrict__ D2,
                                            float* __restrict__ PA64,
                                            float* __restrict__ W22) {
    const int bx = blockIdx.x, tid = threadIdx.x;
    if (bx < 64) {
        const int c = bx >> 2;                  // 0..15 (64-i chunk)
        const int j = (bx & 3) * 256 + tid;
        float pa = 1.0f;
        float2* Dp = (float2*)D2;
#pragma unroll 4
        for (int ip = 0; ip < 32; ++ip) {
            const int i = c * 64 + ip * 2;
            const float wa = sigm(w1[(size_t)i * HID_F + j]);
            const float sa = sigm(s1[(size_t)i * HID_F + j]);
            const float wb = sigm(w1[(size_t)(i + 1) * HID_F + j]);
            const float sb = sigm(s1[(size_t)(i + 1) * HID_F + j]);
            const float A0 = 1.0f - wa * sa, C0 = wa * (2.0f * sa - 1.0f);
            const float A1 = 1.0f - wb * sb, C1 = wb * (2.0f * sb - 1.0f);
            Dp[(size_t)(i >> 1) * HID_F + j] = make_float2(C0 / A0, C1 / A1);
            pa *= A0 * A1;
        }
        PA64[(size_t)c * HID_F + j] = pa;
    } else if (bx < 192) {
        const int idx = bx - 64;                // 0..127
        const int o = (idx & 1) * 256 + tid;
        const int jpg = idx >> 1;               // 0..63
        float2* Wp = (float2*)W22;
#pragma unroll
        for (int p = 0; p < 8; ++p) {
            const int jp = jpg * 8 + p;         // 0..511
            const float a = sigm(w2[(size_t)(2 * jp) * OUT_F + o]);
            const float b = sigm(w2[(size_t)(2 * jp + 1) * OUT_F + o]);
            Wp[(size_t)jp * OUT_F + o] = make_float2(a, b);
        }
    } else {
        __shared__ float tile[32][33];
        const int bt = bx - 192;
        const int i0 = (bt & 31) * 32, b0 = (bt >> 5) * 32;
        const int tx = tid & 31, ty = tid >> 5;
#pragma unroll
        for (int r = 0; r < 32; r += 8)
            tile[ty + r][tx] = x[(size_t)(b0 + ty + r) * IN_F + i0 + tx];
        __syncthreads();
#pragma unroll
        for (int r = 0; r < 32; r += 8)
            xt[(size_t)(i0 + ty + r) * BATCH + b0 + tx] = tile[tx][ty + r];
    }
}

// kA: layer 1 -> ht. grid (16 jg, 16 bg) x 1024 thr (16 waves, i-split 64 each).
// lanes = j: D2 is a per-lane coalesced float2 VMEM stream (deep-pipelined by
// compiler via vmcnt); x[i][b0..b0+8) via s_load batched 8-deep (one lgkm wait
// per 8 i). Packed f32x2 math over b-pairs -> v_pk_fma/v_pk_mul candidates.
// grid.x = jg so the 16 bg-blocks sharing a D2-slice land on one XCD (%8).
__global__ __launch_bounds__(1024, 4) void kA(const float* __restrict__ D2,
                                              const float* __restrict__ PA64,
                                              const float* __restrict__ xt,
                                              float* __restrict__ ht) {
    __shared__ float ps[16][8][64];   // 32 KB
    const int tid  = threadIdx.x;
    const int lane = tid & 63;
    const int wvu  = __builtin_amdgcn_readfirstlane(tid >> 6);  // 0..15
    const int jg = blockIdx.x, bg = blockIdx.y;
    const int j  = jg * 64 + lane;
    const int b0 = bg * 8;
    const int i0w = wvu * 64;

    const float2* dp = (const float2*)D2 + (size_t)(i0w >> 1) * HID_F + j;
    const float pa_v = PA64[(size_t)wvu * HID_F + j];   // per-lane, issued early

    const f32x2 one2 = {1.0f, 1.0f};
    f32x2 acc[4] = {one2, one2, one2, one2};

#define FMA2(XS, DSC) {                                          \
        const f32x2 ds_ = {DSC, DSC};                            \
        acc[0] *= __builtin_elementwise_fma(pair8(XS, 0), ds_, one2); \
        acc[1] *= __builtin_elementwise_fma(pair8(XS, 1), ds_, one2); \
        acc[2] *= __builtin_elementwise_fma(pair8(XS, 2), ds_, one2); \
        acc[3] *= __builtin_elementwise_fma(pair8(XS, 3), ds_, one2); }

#pragma unroll 1
    for (int bt = 0; bt < 8; ++bt) {            // 8 batches of 8 i
        const int ib = i0w + bt * 8;
        const float2 d0 = dp[(size_t)(bt * 4 + 0) * HID_F];   // VMEM stream
        const float2 d1 = dp[(size_t)(bt * 4 + 1) * HID_F];
        const float2 d2 = dp[(size_t)(bt * 4 + 2) * HID_F];
        const float2 d3 = dp[(size_t)(bt * 4 + 3) * HID_F];
        f32x8 x0 = sld8(xt, ((ib + 0) * BATCH + b0) * 4);
        f32x8 x1 = sld8(xt, ((ib + 1) * BATCH + b0) * 4);
        f32x8 x2 = sld8(xt, ((ib + 2) * BATCH + b0) * 4);
        f32x8 x3 = sld8(xt, ((ib + 3) * BATCH + b0) * 4);
        f32x8 x4 = sld8(xt, ((ib + 4) * BATCH + b0) * 4);
        f32x8 x5 = sld8(xt, ((ib + 5) * BATCH + b0) * 4);
        f32x8 x6 = sld8(xt, ((ib + 6) * BATCH + b0) * 4);
        f32x8 x7 = sld8(xt, ((ib + 7) * BATCH + b0) * 4);
        swait8x8(x0, x1, x2, x3, x4, x5, x6, x7);
        FMA2(x0, d0.x); FMA2(x1, d0.y);
        FMA2(x2, d1.x); FMA2(x3, d1.y);
        FMA2(x4, d2.x); FMA2(x5, d2.y);
        FMA2(x6, d3.x); FMA2(x7, d3.y);
    }
#undef FMA2
    const f32x2 pa2 = {pa_v, pa_v};
#pragma unroll
    for (int k = 0; k < 4; ++k) acc[k] *= pa2;

#pragma unroll
    for (int k = 0; k < 4; ++k) {
        ps[wvu][2 * k][lane]     = acc[k].x;
        ps[wvu][2 * k + 1][lane] = acc[k].y;
    }
    __syncthreads();
    if (tid < 512) {
        const int bb = tid >> 6, jj = tid & 63;
        float p = 1.0f;
#pragma unroll
        for (int w = 0; w < 16; ++w) p *= ps[w][bb][jj];
        ht[(size_t)(jg * 64 + jj) * BATCH + b0 + bb] = p;
    }
}

// kB: layer 2 -> out. grid (8 og, 32 bg) x 1024 thr (16 waves, j-split 64).
// lanes = o: W22 per-lane float2 VMEM stream; h via s_load batched 8-deep.
__global__ __launch_bounds__(1024, 4) void kB(const float* __restrict__ W22,
                                              const float* __restrict__ ht,
                                              float* __restrict__ out) {
    __shared__ float ps2[16][4][64];  // 16 KB
    const int tid  = threadIdx.x;
    const int lane = tid & 63;
    const int wvu  = __builtin_amdgcn_readfirstlane(tid >> 6);
    const int og = blockIdx.x, bg = blockIdx.y;
    const int o  = og * 64 + lane;
    const int b0 = bg * 4;
    const int j0w = wvu * 64;

    const float2* wp = (const float2*)W22 + (size_t)(j0w >> 1) * OUT_F + o;

    const f32x2 one2 = {1.0f, 1.0f};
    f32x2 acc[2] = {one2, one2};

#define FMB2(HS, WSC) {                                          \
        const f32x2 ws_ = {WSC, WSC};                            \
        acc[0] *= __builtin_elementwise_fma(-pair4(HS, 0), ws_, one2); \
        acc[1] *= __builtin_elementwise_fma(-pair4(HS, 1), ws_, one2); }

#pragma unroll 1
    for (int bt = 0; bt < 8; ++bt) {            // 8 batches of 8 j
        const int jb = j0w + bt * 8;
        const float2 w0 = wp[(size_t)(bt * 4 + 0) * OUT_F];
        const float2 w1_ = wp[(size_t)(bt * 4 + 1) * OUT_F];
        const float2 w2_ = wp[(size_t)(bt * 4 + 2) * OUT_F];
        const float2 w3_ = wp[(size_t)(bt * 4 + 3) * OUT_F];
        f32x4 h0 = sld4(ht, ((jb + 0) * BATCH + b0) * 4);
        f32x4 h1 = sld4(ht, ((jb + 1) * BATCH + b0) * 4);
        f32x4 h2 = sld4(ht, ((jb + 2) * BATCH + b0) * 4);
        f32x4 h3 = sld4(ht, ((jb + 3) * BATCH + b0) * 4);
        f32x4 h4 = sld4(ht, ((jb + 4) * BATCH + b0) * 4);
        f32x4 h5 = sld4(ht, ((jb + 5) * BATCH + b0) * 4);
        f32x4 h6 = sld4(ht, ((jb + 6) * BATCH + b0) * 4);
        f32x4 h7 = sld4(ht, ((jb + 7) * BATCH + b0) * 4);
        swait4x8(h0, h1, h2, h3, h4, h5, h6, h7);
        FMB2(h0, w0.x); FMB2(h1, w0.y);
        FMB2(h2, w1_.x); FMB2(h3, w1_.y);
        FMB2(h4, w2_.x); FMB2(h5, w2_.y);
        FMB2(h6, w3_.x); FMB2(h7, w3_.y);
    }
#undef FMB2

#pragma unroll
    for (int k = 0; k < 2; ++k) {
        ps2[wvu][2 * k][lane]     = acc[k].x;
        ps2[wvu][2 * k + 1][lane] = acc[k].y;
    }
    __syncthreads();
    if (tid < 256) {
        const int bb = tid >> 6, oo = tid & 63;
        float p = 1.0f;
#pragma unroll
        for (int w = 0; w < 16; ++w) p *= ps2[w][bb][oo];
        out[(size_t)(b0 + bb) * OUT_F + og * 64 + oo] = 1.0f - p;
    }
}

extern "C" void kernel_launch(void* const* d_in, const int* in_sizes, int n_in,
                              void* d_out, int out_size, void* d_ws, size_t ws_size,
                              hipStream_t stream) {
    const float* x  = (const float*)d_in[0];
    const float* w1 = (const float*)d_in[1];
    const float* s1 = (const float*)d_in[2];
    const float* w2 = (const float*)d_in[3];
    float* out = (float*)d_out;

    // ws (floats): D2 4MB | PA64 64KB | W22 2MB | xt 512KB | ht 512KB
    float* D2   = (float*)d_ws;
    float* PA64 = D2 + (size_t)IN_F * HID_F;
    float* W22  = PA64 + (size_t)16 * HID_F;
    float* xt   = W22 + (size_t)HID_F * OUT_F;
    float* ht   = xt + (size_t)IN_F * BATCH;

    kPre<<<320, 256, 0, stream>>>(x, w1, s1, w2, xt, D2, PA64, W22);
    kA<<<dim3(16, 16), 1024, 0, stream>>>(D2, PA64, xt, ht);
    kB<<<dim3(8, 32), 1024, 0, stream>>>(W22, ht, out);
}